// Round 1
// baseline (78.992 us; speedup 1.0000x reference)
//
#include <hip/hip_runtime.h>

// KDE Gaussian: out[l,b] = sum_n exp(-2 * ||samples[b,n,:] - locations[l,:]||^2)
// then pdf[l,b] = out[l,b] / sum_l out[l,b].  Shapes: B=2, N=4096, D=6, L=2048.

#define KDE_B 2
#define KDE_N 4096
#define KDE_D 6

// exp(-2*x) = 2^(x * (-2*log2(e)))
#define NEG2_LOG2E (-2.8853900817779268f)

__global__ void kde_main_kernel(const float* __restrict__ samples,
                                const float* __restrict__ locations,
                                float* __restrict__ out, int L) {
    const int w    = (blockIdx.x * blockDim.x + threadIdx.x) >> 6;  // global wave id
    const int lane = threadIdx.x & 63;
    const int l = w >> 1;          // B == 2
    const int b = w & 1;
    if (l >= L) return;

    float loc[KDE_D];
#pragma unroll
    for (int d = 0; d < KDE_D; ++d) loc[d] = locations[l * KDE_D + d];

    const float* sp = samples + (size_t)b * KDE_N * KDE_D;

    float acc = 0.f;
    for (int n = lane; n < KDE_N; n += 64) {
        const float* s = sp + n * KDE_D;          // 24B-aligned to 8B: 24*n
        float2 s01 = *reinterpret_cast<const float2*>(s);
        float2 s23 = *reinterpret_cast<const float2*>(s + 2);
        float2 s45 = *reinterpret_cast<const float2*>(s + 4);
        float d0 = s01.x - loc[0];
        float d1 = s01.y - loc[1];
        float d2 = s23.x - loc[2];
        float d3 = s23.y - loc[3];
        float d4 = s45.x - loc[4];
        float d5 = s45.y - loc[5];
        float diff2 = d0 * d0;
        diff2 = fmaf(d1, d1, diff2);
        diff2 = fmaf(d2, d2, diff2);
        diff2 = fmaf(d3, d3, diff2);
        diff2 = fmaf(d4, d4, diff2);
        diff2 = fmaf(d5, d5, diff2);
        acc += exp2f(diff2 * NEG2_LOG2E);
    }

    // wave64 butterfly reduce
#pragma unroll
    for (int off = 32; off >= 1; off >>= 1)
        acc += __shfl_xor(acc, off, 64);

    if (lane == 0) out[l * KDE_B + b] = acc;   // layout [L, B] == flat of [1, L, B]
}

__global__ void kde_normalize_kernel(float* __restrict__ out, int L) {
    const int b   = blockIdx.x;      // 0..B-1
    const int tid = threadIdx.x;     // 256 threads

    float s = 0.f;
    for (int l = tid; l < L; l += 256) s += out[l * KDE_B + b];

#pragma unroll
    for (int off = 32; off >= 1; off >>= 1)
        s += __shfl_xor(s, off, 64);

    __shared__ float red[4];
    if ((tid & 63) == 0) red[tid >> 6] = s;
    __syncthreads();
    const float inv = 1.f / (red[0] + red[1] + red[2] + red[3]);

    for (int l = tid; l < L; l += 256) out[l * KDE_B + b] *= inv;
}

extern "C" void kernel_launch(void* const* d_in, const int* in_sizes, int n_in,
                              void* d_out, int out_size, void* d_ws, size_t ws_size,
                              hipStream_t stream) {
    const float* samples   = (const float*)d_in[0];
    const float* locations = (const float*)d_in[1];
    float* out = (float*)d_out;

    const int L = in_sizes[1] / KDE_D;       // 2048
    const int waves = L * KDE_B;             // 4096
    const int threads = 256;
    const int blocks = (waves * 64 + threads - 1) / threads;  // 1024

    kde_main_kernel<<<blocks, threads, 0, stream>>>(samples, locations, out, L);
    kde_normalize_kernel<<<KDE_B, 256, 0, stream>>>(out, L);
}

// Round 2
// 63.497 us; speedup vs baseline: 1.2440x; 1.2440x over previous
//
#include <hip/hip_runtime.h>

// KDE Gaussian: out[l,b] = sum_n exp(-2*||samples[b,n,:]-locations[l,:]||^2),
// pdf[l,b] = out[l,b] / sum_l out[l,b].  B=2, N=4096, D=6, L=2048.
//
// Math: exponent(base2) = C*s2 + C*l2 + sum_d s_d * (-2*C*loc_d),
// C = -2*log2(e).  C*s2 staged per-sample in LDS; C*l2 and scaled loc
// per-location in registers (4 locations/thread).

#define KDE_B 2
#define KDE_N 4096
#define KDE_D 6
#define KDE_L 2048

#define NEG2_LOG2E (-2.8853900817779268f)

#define TL 128        // locations per block
#define LPT 4         // locations per thread
#define NC 256        // samples per block (one chunk)
#define NCHUNK (KDE_N / NC)       // 16
#define LTILES (KDE_L / TL)       // 16

// main: grid = LTILES * NCHUNK * B = 512 blocks x 256 threads
__global__ void __launch_bounds__(256, 2)
kde_main_kernel(const float* __restrict__ samples,
                const float* __restrict__ locations,
                float* __restrict__ ws) {
    const int bid = blockIdx.x;
    const int b  = bid & 1;
    const int c  = (bid >> 1) & (NCHUNK - 1);
    const int lt = bid >> 5;              // 0..15

    const int tid = threadIdx.x;
    const int g   = tid >> 3;             // location group 0..31
    const int sub = tid & 7;              // sample sublane 0..7

    __shared__ float lds[NC * 8];         // [n][8]: s0..s5, C*s2, pad

    // ---- stage NC samples: thread t stages sample t ----
    {
        const float* sp = samples + ((size_t)b * KDE_N + (size_t)c * NC + tid) * KDE_D;
        float2 s01 = *reinterpret_cast<const float2*>(sp);
        float2 s23 = *reinterpret_cast<const float2*>(sp + 2);
        float2 s45 = *reinterpret_cast<const float2*>(sp + 4);
        float s2 = s01.x * s01.x;
        s2 = fmaf(s01.y, s01.y, s2);
        s2 = fmaf(s23.x, s23.x, s2);
        s2 = fmaf(s23.y, s23.y, s2);
        s2 = fmaf(s45.x, s45.x, s2);
        s2 = fmaf(s45.y, s45.y, s2);
        float4* dst = reinterpret_cast<float4*>(&lds[tid * 8]);
        dst[0] = make_float4(s01.x, s01.y, s23.x, s23.y);
        dst[1] = make_float4(s45.x, s45.y, NEG2_LOG2E * s2, 0.f);
    }

    // ---- per-thread locations: lbase .. lbase+3 ----
    const int lbase = lt * TL + g * LPT;
    float lp[LPT][KDE_D];   // -2*C*loc_d
    float A[LPT];           // C*l2
#pragma unroll
    for (int j = 0; j < LPT; ++j) {
        const float* q = locations + (size_t)(lbase + j) * KDE_D;
        float l2 = 0.f;
#pragma unroll
        for (int d = 0; d < KDE_D; ++d) {
            float v = q[d];
            l2 = fmaf(v, v, l2);
            lp[j][d] = (-2.0f * NEG2_LOG2E) * v;
        }
        A[j] = NEG2_LOG2E * l2;
    }

    float acc[LPT] = {0.f, 0.f, 0.f, 0.f};

    __syncthreads();

    const float4* lds4 = reinterpret_cast<const float4*>(lds);
#pragma unroll 4
    for (int k = 0; k < NC / 8; ++k) {
        const int n = (k << 3) | sub;
        float4 sA = lds4[n * 2];        // s0..s3
        float4 sB = lds4[n * 2 + 1];    // s4, s5, C*s2, pad
#pragma unroll
        for (int j = 0; j < LPT; ++j) {
            float e = fmaf(sA.x, lp[j][0], A[j]);
            e = fmaf(sA.y, lp[j][1], e);
            e = fmaf(sA.z, lp[j][2], e);
            e = fmaf(sA.w, lp[j][3], e);
            e = fmaf(sB.x, lp[j][4], e);
            e = fmaf(sB.y, lp[j][5], e);
            e += sB.z;                   // + C*s2
            acc[j] += __builtin_amdgcn_exp2f(e);
        }
    }

    // reduce over 8 sublanes (contiguous lanes within the wave)
#pragma unroll
    for (int j = 0; j < LPT; ++j) {
        float v = acc[j];
        v += __shfl_xor(v, 1, 64);
        v += __shfl_xor(v, 2, 64);
        v += __shfl_xor(v, 4, 64);
        acc[j] = v;
    }
    if (sub == 0) {
#pragma unroll
        for (int j = 0; j < LPT; ++j)
            ws[((size_t)b * NCHUNK + c) * KDE_L + lbase + j] = acc[j];
    }
}

// finalize: 2 blocks (one per b) x 256 threads.
// out[l*2+b] = (sum_c partial[b][c][l]) / norm_b
__global__ void kde_finalize_kernel(const float* __restrict__ ws,
                                    float* __restrict__ out) {
    const int b   = blockIdx.x;
    const int tid = threadIdx.x;
    const float* base = ws + (size_t)b * NCHUNK * KDE_L;

    float vals[KDE_L / 256];
    float norm = 0.f;
#pragma unroll
    for (int i = 0; i < KDE_L / 256; ++i) {
        const int l = tid + i * 256;
        float s = 0.f;
#pragma unroll
        for (int c = 0; c < NCHUNK; ++c)
            s += base[c * KDE_L + l];
        vals[i] = s;
        norm += s;
    }

    // block reduce norm
#pragma unroll
    for (int off = 32; off >= 1; off >>= 1)
        norm += __shfl_xor(norm, off, 64);
    __shared__ float red[4];
    if ((tid & 63) == 0) red[tid >> 6] = norm;
    __syncthreads();
    const float inv = 1.f / (red[0] + red[1] + red[2] + red[3]);

#pragma unroll
    for (int i = 0; i < KDE_L / 256; ++i) {
        const int l = tid + i * 256;
        out[l * KDE_B + b] = vals[i] * inv;
    }
}

extern "C" void kernel_launch(void* const* d_in, const int* in_sizes, int n_in,
                              void* d_out, int out_size, void* d_ws, size_t ws_size,
                              hipStream_t stream) {
    const float* samples   = (const float*)d_in[0];
    const float* locations = (const float*)d_in[1];
    float* out = (float*)d_out;
    float* ws  = (float*)d_ws;

    const int blocks = LTILES * NCHUNK * KDE_B;   // 512
    kde_main_kernel<<<blocks, 256, 0, stream>>>(samples, locations, ws);
    kde_finalize_kernel<<<KDE_B, 256, 0, stream>>>(ws, out);
}